// Round 7
// baseline (215.852 us; speedup 1.0000x reference)
//
#include <hip/hip_runtime.h>

typedef _Float16 half2v __attribute__((ext_vector_type(2)));
typedef _Float16 half4 __attribute__((ext_vector_type(4)));
typedef _Float16 half8 __attribute__((ext_vector_type(8)));
typedef float floatx4 __attribute__((ext_vector_type(4)));

#define B_   8
#define SE   4096
#define SD   4096
#define D_   128
#define NT   64
#define LDB  136
#define LOG2E 1.44269504f

// async 16B global->LDS: per-lane global address, wave-uniform LDS base (+lane*16 by HW)
__device__ __forceinline__ void cp16_async(const _Float16* g, _Float16* l) {
    __builtin_amdgcn_global_load_lds((const __attribute__((address_space(1))) unsigned int*)g,
                                     (__attribute__((address_space(3))) unsigned int*)l, 16, 0, 0);
}

// ---------- prep 0: W16 = fp16(W), Wlo = fp16(W - W16)  (error split) ----------
__global__ __launch_bounds__(256) void wprep(const float* __restrict__ W,
                                             _Float16* __restrict__ W16,
                                             _Float16* __restrict__ Wlo) {
    int i = blockIdx.x * 256 + threadIdx.x;   // grid 64 -> 16384
    float w = W[i];
    _Float16 hi = (_Float16)w;
    W16[i] = hi;
    Wlo[i] = (_Float16)(w - (float)hi);
}

// ---------- prep 1: k' = fp16(b @ W^T) (error-split MFMA), vT = fp16(b^T) ----------
__global__ __launch_bounds__(256) void kvprep(const float* __restrict__ b,
                                              const _Float16* __restrict__ W16,
                                              const _Float16* __restrict__ Wlo,
                                              _Float16* __restrict__ kp,
                                              _Float16* __restrict__ vT) {
    __shared__ _Float16 bs[64 * LDB];   // 17408 B (reused for k' staging)
    const int bb = blockIdx.y, s0 = blockIdx.x * 64;
    const int tid = threadIdx.x, wave = tid >> 6, lane = tid & 63;
    const int l15 = lane & 15, quad = lane >> 4;

    // phase 1: stage fp16(b tile)
    const float* bg = b + ((size_t)bb * SE + s0) * D_;
    #pragma unroll
    for (int it = 0; it < 4; ++it) {
        int idx = tid + it * 256;
        int row = idx >> 4, seg = idx & 15;
        const float* src = bg + row * D_ + seg * 8;
        float4 a = *(const float4*)src;
        float4 c = *(const float4*)(src + 4);
        half8 hv;
        hv[0] = (_Float16)a.x; hv[1] = (_Float16)a.y; hv[2] = (_Float16)a.z; hv[3] = (_Float16)a.w;
        hv[4] = (_Float16)c.x; hv[5] = (_Float16)c.y; hv[6] = (_Float16)c.z; hv[7] = (_Float16)c.w;
        *(half8*)(bs + row * LDB + seg * 8) = hv;
    }
    __syncthreads();

    // phase 2: k'[s][d] = sum_e b[s][e] W[d][e]
    half8 af[4];
    #pragma unroll
    for (int ks = 0; ks < 4; ++ks)
        af[ks] = *(const half8*)(bs + (wave * 16 + l15) * LDB + ks * 32 + quad * 8);
    floatx4 acc[8];
    #pragma unroll
    for (int nt = 0; nt < 8; ++nt) acc[nt] = (floatx4){0.f, 0.f, 0.f, 0.f};
    #pragma unroll
    for (int ks = 0; ks < 4; ++ks) {
        #pragma unroll
        for (int nt = 0; nt < 8; ++nt) {
            half8 bh = *(const half8*)(W16 + (size_t)(nt * 16 + l15) * 128 + ks * 32 + quad * 8);
            half8 bl = *(const half8*)(Wlo + (size_t)(nt * 16 + l15) * 128 + ks * 32 + quad * 8);
            acc[nt] = __builtin_amdgcn_mfma_f32_16x16x32_f16(af[ks], bh, acc[nt], 0, 0, 0);
            acc[nt] = __builtin_amdgcn_mfma_f32_16x16x32_f16(af[ks], bl, acc[nt], 0, 0, 0);
        }
    }

    // phase 3: vT = fp16(b^T): all 256 threads, 4s x 8d micro-transpose each
    {
        const int sq = tid & 15, dg = tid >> 4;   // s = sq*4 .. +3, d = dg*8 .. +7
        half8 rowv[4];
        #pragma unroll
        for (int j = 0; j < 4; ++j)
            rowv[j] = *(const half8*)(bs + (sq * 4 + j) * LDB + dg * 8);
        #pragma unroll
        for (int r = 0; r < 8; ++r) {
            int d = dg * 8 + r;
            half4 o;
            #pragma unroll
            for (int j = 0; j < 4; ++j) o[j] = rowv[j][r];
            *(half4*)(vT + ((size_t)bb * D_ + d) * SE + s0 + sq * 4) = o;
        }
    }
    __syncthreads();

    // phase 4: k' C-frags -> bs (overwrite), then coalesced row-major writeout
    #pragma unroll
    for (int nt = 0; nt < 8; ++nt)
        #pragma unroll
        for (int r = 0; r < 4; ++r)
            bs[(wave * 16 + quad * 4 + r) * LDB + nt * 16 + l15] = (_Float16)acc[nt][r];
    __syncthreads();
    _Float16* kg = kp + ((size_t)bb * SE + s0) * D_;
    {
        const int row = tid >> 2;
        #pragma unroll
        for (int it = 0; it < 4; ++it) {
            int ch = (tid & 3) + it * 4;
            half8 v = *(const half8*)(bs + row * LDB + ch * 8);
            *(half8*)(kg + row * D_ + ch * 8) = v;
        }
    }
}

// ---------- fused flash attention, s-split across waves ----------
// Waves = 2 q-groups (wq) x 2 s-groups (ws). Each wave: 32 q rows x its 32-s
// half per tile -> half the LDS reads of the q-only split; V frags shared
// across the wave's two q-tiles. Per-wave (m,l,O) merged exactly in epilogue.
__global__ __launch_bounds__(256, 2) void flash(const float* __restrict__ h,
                                                const _Float16* __restrict__ k,
                                                const _Float16* __restrict__ vT,
                                                float* __restrict__ out) {
    __shared__ _Float16 KV[2][16384];   // per buf: K image 8192 halves + V image 8192

    const int bb   = blockIdx.y;
    const int q0   = blockIdx.x * 64;
    const int tid  = threadIdx.x;
    const int wave = tid >> 6;
    const int wq   = wave >> 1;        // q-group 0..1 (32 q rows each)
    const int ws   = wave & 1;         // s-group 0..1 (32 s each per tile)
    const int lane = tid & 63;
    const int l15  = lane & 15;
    const int quad = lane >> 4;

    const _Float16* kbase = k + (size_t)bb * SE * D_;
    const _Float16* vbase = vT + (size_t)bb * D_ * SE;

    // per-lane DMA gather offsets (XOR-swizzled chunk images, whole block cooperates)
    int koff[4], voff[4];
    #pragma unroll
    for (int j = 0; j < 4; ++j) {
        int i = (wave * 4 + j) * 64 + lane;
        int kr = i >> 4, kpp = i & 15;
        koff[j] = kr * D_ + (kpp ^ (kr & 15)) * 8;
        int vr = i >> 3, vpp = i & 7;
        voff[j] = vr * SE + (vpp ^ (vr & 7)) * 8;
    }

    // hoisted LDS read bases; inner loop uses imm offsets (stl*2048 / dt*1024 halves)
    const _Float16* kA0[4]; const _Float16* kA1[4];
    const _Float16* vB0[2]; const _Float16* vB1[2];
    #pragma unroll
    for (int ks = 0; ks < 4; ++ks) {
        int o = l15 * 128 + (((ks * 4 + quad) ^ l15) * 8) + ws * 4096;
        kA0[ks] = &KV[0][o]; kA1[ks] = &KV[1][o];
    }
    #pragma unroll
    for (int stl = 0; stl < 2; ++stl) {
        int o = 8192 + l15 * 64 + (((ws * 4 + stl * 2 + (quad >> 1)) ^ (l15 & 7)) * 8) + (quad & 1) * 4;
        vB0[stl] = &KV[0][o]; vB1[stl] = &KV[1][o];
    }

    // issue tile 0 DMA
    {
        _Float16* buf0 = &KV[0][0];
        #pragma unroll
        for (int j = 0; j < 4; ++j) {
            cp16_async(kbase + koff[j], buf0 + (wave * 4 + j) * 512);
            cp16_async(vbase + voff[j], buf0 + 8192 + (wave * 4 + j) * 512);
        }
    }

    // Q = fp16(h * log2e) B-fragments for the wave's two q-tiles
    half8 qf[2][4];
    #pragma unroll
    for (int qt = 0; qt < 2; ++qt) {
        const float* hrow = h + ((size_t)bb * SD + q0 + wq * 32 + qt * 16 + l15) * D_;
        #pragma unroll
        for (int ks = 0; ks < 4; ++ks) {
            float4 a = *(const float4*)(hrow + ks * 32 + quad * 8);
            float4 c = *(const float4*)(hrow + ks * 32 + quad * 8 + 4);
            half8 f;
            f[0] = (_Float16)(a.x * LOG2E); f[1] = (_Float16)(a.y * LOG2E);
            f[2] = (_Float16)(a.z * LOG2E); f[3] = (_Float16)(a.w * LOG2E);
            f[4] = (_Float16)(c.x * LOG2E); f[5] = (_Float16)(c.y * LOG2E);
            f[6] = (_Float16)(c.z * LOG2E); f[7] = (_Float16)(c.w * LOG2E);
            qf[qt][ks] = f;
        }
    }

    floatx4 acc_o[2][8];
    #pragma unroll
    for (int qt = 0; qt < 2; ++qt)
        #pragma unroll
        for (int dt = 0; dt < 8; ++dt) acc_o[qt][dt] = (floatx4){0.f, 0.f, 0.f, 0.f};
    float m_q[2] = {-1e30f, -1e30f};
    float l_part[2] = {0.f, 0.f};
    const half2v one2 = { (_Float16)1.f, (_Float16)1.f };

    for (int t = 0; t < SE / NT; ++t) {
        __syncthreads();   // vmcnt drain -> tile t landed for all waves
        if (t + 1 < SE / NT) {
            const _Float16* kt = kbase + (size_t)(t + 1) * (NT * D_);
            const _Float16* vt = vbase + (size_t)(t + 1) * NT;
            _Float16* bufn = &KV[(t + 1) & 1][0];
            #pragma unroll
            for (int j = 0; j < 4; ++j) {
                cp16_async(kt + koff[j], bufn + (wave * 4 + j) * 512);
                cp16_async(vt + voff[j], bufn + 8192 + (wave * 4 + j) * 512);
            }
        }
        const bool odd = (t & 1) != 0;
        const _Float16* kA[4]; const _Float16* vB[2];
        #pragma unroll
        for (int i = 0; i < 4; ++i) kA[i] = odd ? kA1[i] : kA0[i];
        #pragma unroll
        for (int i = 0; i < 2; ++i) vB[i] = odd ? vB1[i] : vB0[i];

        // S^T = K Q^T for ws's 32-s half: accs[stl][qt], C row s=quad*4+r, col q=l15
        floatx4 accs[2][2];
        #pragma unroll
        for (int stl = 0; stl < 2; ++stl)
            #pragma unroll
            for (int qt = 0; qt < 2; ++qt) accs[stl][qt] = (floatx4){0.f, 0.f, 0.f, 0.f};
        #pragma unroll
        for (int ks = 0; ks < 4; ++ks) {
            half8 af0 = *(const half8*)(kA[ks]);
            half8 af1 = *(const half8*)(kA[ks] + 2048);
            accs[0][0] = __builtin_amdgcn_mfma_f32_16x16x32_f16(af0, qf[0][ks], accs[0][0], 0, 0, 0);
            accs[0][1] = __builtin_amdgcn_mfma_f32_16x16x32_f16(af0, qf[1][ks], accs[0][1], 0, 0, 0);
            accs[1][0] = __builtin_amdgcn_mfma_f32_16x16x32_f16(af1, qf[0][ks], accs[1][0], 0, 0, 0);
            accs[1][1] = __builtin_amdgcn_mfma_f32_16x16x32_f16(af1, qf[1][ks], accs[1][1], 0, 0, 0);
        }

        // deferred-rescale online softmax (per qt; fast path: no cross-lane ops)
        float mv[2];
        #pragma unroll
        for (int qt = 0; qt < 2; ++qt) {
            float a = fmaxf(fmaxf(accs[0][qt][0], accs[0][qt][1]), fmaxf(accs[0][qt][2], accs[0][qt][3]));
            float b2 = fmaxf(fmaxf(accs[1][qt][0], accs[1][qt][1]), fmaxf(accs[1][qt][2], accs[1][qt][3]));
            mv[qt] = fmaxf(a, b2);
        }
        bool cond = (mv[0] > m_q[0] + 11.5f) || (mv[1] > m_q[1] + 11.5f);
        if (__ballot(cond) != 0ull) {        // rare wave-uniform slow path
            #pragma unroll
            for (int qt = 0; qt < 2; ++qt) {
                float m = mv[qt];
                m = fmaxf(m, __shfl_xor(m, 16, 64));
                m = fmaxf(m, __shfl_xor(m, 32, 64));
                float mnew = fmaxf(m_q[qt], m);
                float alpha = exp2f(m_q[qt] - mnew);
                l_part[qt] *= alpha;
                float ab[4];
                #pragma unroll
                for (int r = 0; r < 4; ++r) ab[r] = __shfl(alpha, quad * 4 + r, 64);
                #pragma unroll
                for (int dt = 0; dt < 8; ++dt)
                    #pragma unroll
                    for (int r = 0; r < 4; ++r) acc_o[qt][dt][r] *= ab[r];
                m_q[qt] = mnew;
            }
        }

        // P = 2^(S^T - m); pf[qt][stl] IS the PV A-fragment
        half4 pf[2][2];
        #pragma unroll
        for (int qt = 0; qt < 2; ++qt)
            #pragma unroll
            for (int stl = 0; stl < 2; ++stl) {
                float p0 = exp2f(accs[stl][qt][0] - m_q[qt]);
                float p1 = exp2f(accs[stl][qt][1] - m_q[qt]);
                float p2 = exp2f(accs[stl][qt][2] - m_q[qt]);
                float p3 = exp2f(accs[stl][qt][3] - m_q[qt]);
                half2v lo = __builtin_bit_cast(half2v, __builtin_amdgcn_cvt_pkrtz(p0, p1));
                half2v hi = __builtin_bit_cast(half2v, __builtin_amdgcn_cvt_pkrtz(p2, p3));
#if __has_builtin(__builtin_amdgcn_fdot2)
                l_part[qt] = __builtin_amdgcn_fdot2(lo, one2, l_part[qt], false);
                l_part[qt] = __builtin_amdgcn_fdot2(hi, one2, l_part[qt], false);
#else
                l_part[qt] += p0 + p1 + p2 + p3;
#endif
                half4 pv; pv[0] = lo[0]; pv[1] = lo[1]; pv[2] = hi[0]; pv[3] = hi[1];
                pf[qt][stl] = pv;
            }

        // O += P V : V frag shared across the two q-tiles
        #pragma unroll
        for (int stl = 0; stl < 2; ++stl) {
            #pragma unroll
            for (int dt = 0; dt < 8; ++dt) {
                half4 vf = *(const half4*)(vB[stl] + dt * 1024);
                acc_o[0][dt] = __builtin_amdgcn_mfma_f32_16x16x16f16(pf[0][stl], vf, acc_o[0][dt], 0, 0, 0);
                acc_o[1][dt] = __builtin_amdgcn_mfma_f32_16x16x16f16(pf[1][stl], vf, acc_o[1][dt], 0, 0, 0);
            }
        }
    }

    // ---- epilogue: finalize per-wave partials, exact cross-wave (s-split) merge ----
    float l_own[2];
    #pragma unroll
    for (int qt = 0; qt < 2; ++qt) {
        float l = l_part[qt];
        l += __shfl_xor(l, 16, 64);
        l += __shfl_xor(l, 32, 64);
        l_own[qt] = l;                 // denominator partial for q = l15 (uniform over quads)
    }

    __syncthreads();                   // all PV reads of KV done; safe to overwrite
    float* Ob = (float*)&KV[0][0];     // 2 wq x 16 KB of O1 fragments (float4-indexed)
    float* ml = (float*)&KV[0][0] + 8192;  // m,l pairs: [wq][32 q][2]

    if (ws == 1) {
        #pragma unroll
        for (int qt = 0; qt < 2; ++qt) {
            #pragma unroll
            for (int dt = 0; dt < 8; ++dt)
                *(floatx4*)(Ob + (((wq * 2 + qt) * 8 + dt) * 64 + lane) * 4) = acc_o[qt][dt];
            if (quad == 0)
                *(float2*)(ml + (wq * 32 + qt * 16 + l15) * 2) = make_float2(m_q[qt], l_own[qt]);
        }
    }
    __syncthreads();
    if (ws == 0) {
        #pragma unroll
        for (int qt = 0; qt < 2; ++qt) {
            float m0r[4], l0r[4], m1r[4], l1r[4];
            #pragma unroll
            for (int r = 0; r < 4; ++r) {
                m0r[r] = __shfl(m_q[qt], quad * 4 + r, 64);
                l0r[r] = __shfl(l_own[qt], quad * 4 + r, 64);
                float2 p = *(float2*)(ml + (wq * 32 + qt * 16 + quad * 4 + r) * 2);
                m1r[r] = p.x; l1r[r] = p.y;
            }
            float a0[4], a1[4], inv[4];
            #pragma unroll
            for (int r = 0; r < 4; ++r) {
                float mm = fmaxf(m0r[r], m1r[r]);
                a0[r] = exp2f(m0r[r] - mm);
                a1[r] = exp2f(m1r[r] - mm);
                inv[r] = 1.f / (l0r[r] * a0[r] + l1r[r] * a1[r]);
            }
            float* orow = out + ((size_t)bb * SD + q0 + wq * 32 + qt * 16 + quad * 4) * D_;
            #pragma unroll
            for (int dt = 0; dt < 8; ++dt) {
                floatx4 o1 = *(floatx4*)(Ob + (((wq * 2 + qt) * 8 + dt) * 64 + lane) * 4);
                #pragma unroll
                for (int r = 0; r < 4; ++r)
                    orow[(size_t)r * D_ + dt * 16 + l15] =
                        (acc_o[qt][dt][r] * a0[r] + o1[r] * a1[r]) * inv[r];
            }
        }
    }
}

extern "C" void kernel_launch(void* const* d_in, const int* in_sizes, int n_in,
                              void* d_out, int out_size, void* d_ws, size_t ws_size,
                              hipStream_t stream) {
    const float* b = (const float*)d_in[0];   // [B, SE, D]
    const float* h = (const float*)d_in[1];   // [B, SD, D]
    const float* W = (const float*)d_in[2];   // [D, D]
    float* out = (float*)d_out;               // [B, SD, D] fp32

    _Float16* W16 = (_Float16*)d_ws;                       // 32 KB
    _Float16* Wlo = W16 + 128 * 128;                       // 32 KB
    _Float16* kp  = Wlo + 128 * 128;                       // [B, SE, D] fp16
    _Float16* vT  = kp + (size_t)B_ * SE * D_;             // [B, D, SE] fp16

    wprep<<<64, 256, 0, stream>>>(W, W16, Wlo);
    kvprep<<<dim3(SE / 64, B_), 256, 0, stream>>>(b, W16, Wlo, kp, vT);
    flash<<<dim3(SD / 64, B_), 256, 0, stream>>>(h, kp, vT, out);
}

// Round 9
// 208.470 us; speedup vs baseline: 1.0354x; 1.0354x over previous
//
#include <hip/hip_runtime.h>

typedef _Float16 half2v __attribute__((ext_vector_type(2)));
typedef _Float16 half4 __attribute__((ext_vector_type(4)));
typedef _Float16 half8 __attribute__((ext_vector_type(8)));
typedef float floatx4 __attribute__((ext_vector_type(4)));

#define B_   8
#define SE   4096
#define SD   4096
#define D_   128
#define NT   64      // K/V rows per tile (round-7 verified geometry)
#define LDB  136
#define LOG2E 1.44269504f

// async 16B global->LDS: per-lane global address, wave-uniform LDS base (+lane*16 by HW)
__device__ __forceinline__ void cp16_async(const _Float16* g, _Float16* l) {
    __builtin_amdgcn_global_load_lds((const __attribute__((address_space(1))) unsigned int*)g,
                                     (__attribute__((address_space(3))) unsigned int*)l, 16, 0, 0);
}

// ---------- prep 0: W16 = fp16(W), Wlo = fp16(W - W16)  (error split) ----------
__global__ __launch_bounds__(256) void wprep(const float* __restrict__ W,
                                             _Float16* __restrict__ W16,
                                             _Float16* __restrict__ Wlo) {
    int i = blockIdx.x * 256 + threadIdx.x;   // grid 64 -> 16384
    float w = W[i];
    _Float16 hi = (_Float16)w;
    W16[i] = hi;
    Wlo[i] = (_Float16)(w - (float)hi);
}

// ---------- prep 1: k' = fp16(b @ W^T) (error-split MFMA), vT = fp16(b^T) ----------
__global__ __launch_bounds__(256) void kvprep(const float* __restrict__ b,
                                              const _Float16* __restrict__ W16,
                                              const _Float16* __restrict__ Wlo,
                                              _Float16* __restrict__ kp,
                                              _Float16* __restrict__ vT) {
    __shared__ _Float16 bs[64 * LDB];   // 17408 B (reused for k' staging)
    const int bb = blockIdx.y, s0 = blockIdx.x * 64;
    const int tid = threadIdx.x, wave = tid >> 6, lane = tid & 63;
    const int l15 = lane & 15, quad = lane >> 4;

    // phase 1: stage fp16(b tile)
    const float* bg = b + ((size_t)bb * SE + s0) * D_;
    #pragma unroll
    for (int it = 0; it < 4; ++it) {
        int idx = tid + it * 256;
        int row = idx >> 4, seg = idx & 15;
        const float* src = bg + row * D_ + seg * 8;
        float4 a = *(const float4*)src;
        float4 c = *(const float4*)(src + 4);
        half8 hv;
        hv[0] = (_Float16)a.x; hv[1] = (_Float16)a.y; hv[2] = (_Float16)a.z; hv[3] = (_Float16)a.w;
        hv[4] = (_Float16)c.x; hv[5] = (_Float16)c.y; hv[6] = (_Float16)c.z; hv[7] = (_Float16)c.w;
        *(half8*)(bs + row * LDB + seg * 8) = hv;
    }
    __syncthreads();

    // phase 2: k'[s][d] = sum_e b[s][e] W[d][e]
    half8 af[4];
    #pragma unroll
    for (int ks = 0; ks < 4; ++ks)
        af[ks] = *(const half8*)(bs + (wave * 16 + l15) * LDB + ks * 32 + quad * 8);
    floatx4 acc[8];
    #pragma unroll
    for (int nt = 0; nt < 8; ++nt) acc[nt] = (floatx4){0.f, 0.f, 0.f, 0.f};
    #pragma unroll
    for (int ks = 0; ks < 4; ++ks) {
        #pragma unroll
        for (int nt = 0; nt < 8; ++nt) {
            half8 bh = *(const half8*)(W16 + (size_t)(nt * 16 + l15) * 128 + ks * 32 + quad * 8);
            half8 bl = *(const half8*)(Wlo + (size_t)(nt * 16 + l15) * 128 + ks * 32 + quad * 8);
            acc[nt] = __builtin_amdgcn_mfma_f32_16x16x32_f16(af[ks], bh, acc[nt], 0, 0, 0);
            acc[nt] = __builtin_amdgcn_mfma_f32_16x16x32_f16(af[ks], bl, acc[nt], 0, 0, 0);
        }
    }

    // phase 3: vT = fp16(b^T): all 256 threads, 4s x 8d micro-transpose each
    {
        const int sq = tid & 15, dg = tid >> 4;   // s = sq*4 .. +3, d = dg*8 .. +7
        half8 rowv[4];
        #pragma unroll
        for (int j = 0; j < 4; ++j)
            rowv[j] = *(const half8*)(bs + (sq * 4 + j) * LDB + dg * 8);
        #pragma unroll
        for (int r = 0; r < 8; ++r) {
            int d = dg * 8 + r;
            half4 o;
            #pragma unroll
            for (int j = 0; j < 4; ++j) o[j] = rowv[j][r];
            *(half4*)(vT + ((size_t)bb * D_ + d) * SE + s0 + sq * 4) = o;
        }
    }
    __syncthreads();

    // phase 4: k' C-frags -> bs (overwrite), then coalesced row-major writeout
    #pragma unroll
    for (int nt = 0; nt < 8; ++nt)
        #pragma unroll
        for (int r = 0; r < 4; ++r)
            bs[(wave * 16 + quad * 4 + r) * LDB + nt * 16 + l15] = (_Float16)acc[nt][r];
    __syncthreads();
    _Float16* kg = kp + ((size_t)bb * SE + s0) * D_;
    {
        const int row = tid >> 2;
        #pragma unroll
        for (int it = 0; it < 4; ++it) {
            int ch = (tid & 3) + it * 4;
            half8 v = *(const half8*)(bs + row * LDB + ch * 8);
            *(half8*)(kg + row * D_ + ch * 8) = v;
        }
    }
}

// ---------- fused flash attention: round-7 tile geometry, 512-thread blocks ----------
// 8 waves = 4 q-groups (wq, 16 q rows) x 2 s-groups (ws, 32 s per tile).
// Same NT=64 K/V images, XOR swizzles, and DMA formulas as the verified round-7
// kernel; only thread roles / DMA round count / epilogue sizes changed.
// 64 KB LDS -> 2 blocks/CU x 8 waves = 4 waves/SIMD (2x round 7).
__global__ __launch_bounds__(512, 4) void flash(const float* __restrict__ h,
                                                const _Float16* __restrict__ k,
                                                const _Float16* __restrict__ vT,
                                                float* __restrict__ out) {
    __shared__ _Float16 KV[2][16384];   // per buf: K image 8192 halves + V image 8192

    const int bb   = blockIdx.y;
    const int q0   = blockIdx.x * 64;
    const int tid  = threadIdx.x;      // 0..511
    const int wave = tid >> 6;         // 0..7
    const int wq   = wave >> 1;        // q-group 0..3 (16 q rows each)
    const int ws   = wave & 1;         // s-group 0..1 (32 s each per tile)
    const int lane = tid & 63;
    const int l15  = lane & 15;
    const int quad = lane >> 4;

    const _Float16* kbase = k + (size_t)bb * SE * D_;
    const _Float16* vbase = vT + (size_t)bb * D_ * SE;

    // per-lane DMA gather offsets (round-7 formulas); 1024 chunks per image,
    // 2 rounds of 512 threads
    int koff[2], voff[2];
    #pragma unroll
    for (int it = 0; it < 2; ++it) {
        int i = it * 512 + wave * 64 + lane;      // linear 16B chunk index in image
        int kr = i >> 4, kpp = i & 15;            // K: 64 rows x 16 chunks
        koff[it] = kr * D_ + (kpp ^ (kr & 15)) * 8;
        int vr = i >> 3, vpp = i & 7;             // V: 128 rows x 8 chunks
        voff[it] = vr * SE + (vpp ^ (vr & 7)) * 8;
    }

    // hoisted LDS read bases (round-7 formulas); imm offsets stl*2048 / dt*1024
    const _Float16* kA0[4]; const _Float16* kA1[4];
    const _Float16* vB0[2]; const _Float16* vB1[2];
    #pragma unroll
    for (int ks = 0; ks < 4; ++ks) {
        int o = l15 * 128 + (((ks * 4 + quad) ^ l15) * 8) + ws * 4096;
        kA0[ks] = &KV[0][o]; kA1[ks] = &KV[1][o];
    }
    #pragma unroll
    for (int stl = 0; stl < 2; ++stl) {
        int o = 8192 + l15 * 64 + (((ws * 4 + stl * 2 + (quad >> 1)) ^ (l15 & 7)) * 8) + (quad & 1) * 4;
        vB0[stl] = &KV[0][o]; vB1[stl] = &KV[1][o];
    }

    // issue tile 0 DMA
    {
        _Float16* buf0 = &KV[0][0];
        #pragma unroll
        for (int it = 0; it < 2; ++it) {
            cp16_async(kbase + koff[it], buf0 + (it * 512 + wave * 64) * 8);
            cp16_async(vbase + voff[it], buf0 + 8192 + (it * 512 + wave * 64) * 8);
        }
    }

    // Q = fp16(h * log2e) B-fragments (16 q rows for this wq)
    half8 qf[4];
    {
        const float* hrow = h + ((size_t)bb * SD + q0 + wq * 16 + l15) * D_;
        #pragma unroll
        for (int ks = 0; ks < 4; ++ks) {
            float4 a = *(const float4*)(hrow + ks * 32 + quad * 8);
            float4 c = *(const float4*)(hrow + ks * 32 + quad * 8 + 4);
            half8 f;
            f[0] = (_Float16)(a.x * LOG2E); f[1] = (_Float16)(a.y * LOG2E);
            f[2] = (_Float16)(a.z * LOG2E); f[3] = (_Float16)(a.w * LOG2E);
            f[4] = (_Float16)(c.x * LOG2E); f[5] = (_Float16)(c.y * LOG2E);
            f[6] = (_Float16)(c.z * LOG2E); f[7] = (_Float16)(c.w * LOG2E);
            qf[ks] = f;
        }
    }

    floatx4 acc_o[8];
    #pragma unroll
    for (int dt = 0; dt < 8; ++dt) acc_o[dt] = (floatx4){0.f, 0.f, 0.f, 0.f};
    float m_q = -1e30f;   // running max (base-2), uniform across quads, per q=l15
    float l_part = 0.f;   // per-lane partial denominator
    const half2v one2 = { (_Float16)1.f, (_Float16)1.f };

    for (int t = 0; t < SE / NT; ++t) {
        __syncthreads();   // vmcnt drain -> tile t landed for all waves
        if (t + 1 < SE / NT) {
            const _Float16* kt = kbase + (size_t)(t + 1) * (NT * D_);
            const _Float16* vt = vbase + (size_t)(t + 1) * NT;
            _Float16* bufn = &KV[(t + 1) & 1][0];
            #pragma unroll
            for (int it = 0; it < 2; ++it) {
                cp16_async(kt + koff[it], bufn + (it * 512 + wave * 64) * 8);
                cp16_async(vt + voff[it], bufn + 8192 + (it * 512 + wave * 64) * 8);
            }
        }
        const bool odd = (t & 1) != 0;
        const _Float16* vB[2];
        vB[0] = odd ? vB1[0] : vB0[0];
        vB[1] = odd ? vB1[1] : vB0[1];

        // S^T = K Q^T for this wave's 32 s (2 subtiles): C row s=quad*4+r, col q=l15
        floatx4 accs[2];
        accs[0] = (floatx4){0.f, 0.f, 0.f, 0.f};
        accs[1] = (floatx4){0.f, 0.f, 0.f, 0.f};
        #pragma unroll
        for (int ks = 0; ks < 4; ++ks) {
            const _Float16* ka = odd ? kA1[ks] : kA0[ks];
            half8 af0 = *(const half8*)(ka);
            half8 af1 = *(const half8*)(ka + 2048);
            accs[0] = __builtin_amdgcn_mfma_f32_16x16x32_f16(af0, qf[ks], accs[0], 0, 0, 0);
            accs[1] = __builtin_amdgcn_mfma_f32_16x16x32_f16(af1, qf[ks], accs[1], 0, 0, 0);
        }

        // deferred-rescale online softmax, base-2 (fast path: no cross-lane ops)
        float mv = fmaxf(fmaxf(fmaxf(accs[0][0], accs[0][1]), fmaxf(accs[0][2], accs[0][3])),
                         fmaxf(fmaxf(accs[1][0], accs[1][1]), fmaxf(accs[1][2], accs[1][3])));
        if (__ballot(mv > m_q + 11.5f) != 0ull) {   // rare wave-uniform slow path
            float m = mv;
            m = fmaxf(m, __shfl_xor(m, 16, 64));
            m = fmaxf(m, __shfl_xor(m, 32, 64));
            float mnew = fmaxf(m_q, m);
            float alpha = exp2f(m_q - mnew);
            l_part *= alpha;
            float ab[4];
            #pragma unroll
            for (int r = 0; r < 4; ++r) ab[r] = __shfl(alpha, quad * 4 + r, 64);
            #pragma unroll
            for (int dt = 0; dt < 8; ++dt)
                #pragma unroll
                for (int r = 0; r < 4; ++r) acc_o[dt][r] *= ab[r];
            m_q = mnew;
        }

        // P = 2^(S^T - m); pf[stl] IS the PV A-fragment (m=q=l15, k=s=quad*4+r)
        half4 pf[2];
        #pragma unroll
        for (int stl = 0; stl < 2; ++stl) {
            float p0 = exp2f(accs[stl][0] - m_q);
            float p1 = exp2f(accs[stl][1] - m_q);
            float p2 = exp2f(accs[stl][2] - m_q);
            float p3 = exp2f(accs[stl][3] - m_q);
            half2v lo = __builtin_bit_cast(half2v, __builtin_amdgcn_cvt_pkrtz(p0, p1));
            half2v hi = __builtin_bit_cast(half2v, __builtin_amdgcn_cvt_pkrtz(p2, p3));
#if __has_builtin(__builtin_amdgcn_fdot2)
            l_part = __builtin_amdgcn_fdot2(lo, one2, l_part, false);
            l_part = __builtin_amdgcn_fdot2(hi, one2, l_part, false);
#else
            l_part += p0 + p1 + p2 + p3;
#endif
            half4 pv; pv[0] = lo[0]; pv[1] = lo[1]; pv[2] = hi[0]; pv[3] = hi[1];
            pf[stl] = pv;
        }

        // O += P V : B-frag = V^T[d=dt*16+l15][s=ws*32+stl*16+quad*4..+3]
        #pragma unroll
        for (int stl = 0; stl < 2; ++stl) {
            #pragma unroll
            for (int dt = 0; dt < 8; ++dt) {
                half4 vf = *(const half4*)(vB[stl] + dt * 1024);
                acc_o[dt] = __builtin_amdgcn_mfma_f32_16x16x16f16(pf[stl], vf, acc_o[dt], 0, 0, 0);
            }
        }
    }

    // ---- epilogue: finalize per-wave partials, exact cross-wave (s-split) merge ----
    float l_own;
    {
        float l = l_part;
        l += __shfl_xor(l, 16, 64);
        l += __shfl_xor(l, 32, 64);
        l_own = l;                     // denominator partial for q = l15
    }

    __syncthreads();                   // all PV reads of KV done; safe to overwrite
    float* Ob = (float*)&KV[0][0];     // [wq][dt][lane] float4 : 32 KB (8192 floats)
    float* ml = (float*)&KV[1][0];     // m,l pairs: [wq*16 + q][2]  (128 floats)

    if (ws == 1) {
        #pragma unroll
        for (int dt = 0; dt < 8; ++dt)
            *(floatx4*)(Ob + ((wq * 8 + dt) * 64 + lane) * 4) = acc_o[dt];
        if (quad == 0)
            *(float2*)(ml + (wq * 16 + l15) * 2) = make_float2(m_q, l_own);
    }
    __syncthreads();
    if (ws == 0) {
        float m0r[4], l0r[4], m1r[4], l1r[4];
        #pragma unroll
        for (int r = 0; r < 4; ++r) {
            m0r[r] = __shfl(m_q, quad * 4 + r, 64);
            l0r[r] = __shfl(l_own, quad * 4 + r, 64);
            float2 p = *(float2*)(ml + (wq * 16 + quad * 4 + r) * 2);
            m1r[r] = p.x; l1r[r] = p.y;
        }
        float a0[4], a1[4], inv[4];
        #pragma unroll
        for (int r = 0; r < 4; ++r) {
            float mm = fmaxf(m0r[r], m1r[r]);
            a0[r] = exp2f(m0r[r] - mm);
            a1[r] = exp2f(m1r[r] - mm);
            inv[r] = 1.f / (l0r[r] * a0[r] + l1r[r] * a1[r]);
        }
        float* orow = out + ((size_t)bb * SD + q0 + wq * 16 + quad * 4) * D_;
        #pragma unroll
        for (int dt = 0; dt < 8; ++dt) {
            floatx4 o1 = *(floatx4*)(Ob + ((wq * 8 + dt) * 64 + lane) * 4);
            #pragma unroll
            for (int r = 0; r < 4; ++r)
                orow[(size_t)r * D_ + dt * 16 + l15] =
                    (acc_o[dt][r] * a0[r] + o1[r] * a1[r]) * inv[r];
        }
    }
}

extern "C" void kernel_launch(void* const* d_in, const int* in_sizes, int n_in,
                              void* d_out, int out_size, void* d_ws, size_t ws_size,
                              hipStream_t stream) {
    const float* b = (const float*)d_in[0];   // [B, SE, D]
    const float* h = (const float*)d_in[1];   // [B, SD, D]
    const float* W = (const float*)d_in[2];   // [D, D]
    float* out = (float*)d_out;               // [B, SD, D] fp32

    _Float16* W16 = (_Float16*)d_ws;                       // 32 KB
    _Float16* Wlo = W16 + 128 * 128;                       // 32 KB
    _Float16* kp  = Wlo + 128 * 128;                       // [B, SE, D] fp16
    _Float16* vT  = kp + (size_t)B_ * SE * D_;             // [B, D, SE] fp16

    wprep<<<64, 256, 0, stream>>>(W, W16, Wlo);
    kvprep<<<dim3(SE / 64, B_), 256, 0, stream>>>(b, W16, Wlo, kp, vT);
    flash<<<dim3(SD / 64, B_), 512, 0, stream>>>(h, kp, vT, out);
}